// Round 2
// baseline (323.116 us; speedup 1.0000x reference)
//
#include <hip/hip_runtime.h>
#include <cstddef>

#define NT 10            // NUM_TOKENS
#define TD 96            // TOKEN_DIM == REF_DIM
#define NH 4             // NUM_HEADS
#define NPOS (32 * 2048) // B*T positions
#define TPB 256
#define LPP 4            // lanes per position
#define DPL 24           // d's per lane (TD / LPP)

__device__ __forceinline__ float fast_tanh(float x) {
    // tanh(x) = 1 - 2/(exp(2x)+1); exact limits at +/-inf, ~1e-6 rel error
    float e = __expf(2.0f * x);
    return 1.0f - 2.0f * __builtin_amdgcn_rcpf(e + 1.0f);
}

__global__ __launch_bounds__(TPB, 4) void gst_fused(
    const float* __restrict__ ref_emb,
    const float* __restrict__ tokens,
    const float* __restrict__ Wq,
    const float* __restrict__ Wk,
    const float* __restrict__ Wv,
    float* __restrict__ out)
{
    // kT[d][n] = tanh(tokens @ Wk^T) transposed; rows padded to 12 floats (48B,
    // 16B-aligned so we can ds_read_b128 them)
    __shared__ __align__(16) float kT[TD][12];
    __shared__ __align__(16) float wvT[TD][4];   // wvT[d][h] = Wv[h][d]
    __shared__ __align__(16) float tokS[NT][TD]; // tokens staged for style stage

    for (int idx = threadIdx.x; idx < NT * TD; idx += TPB) {
        int n = idx / TD;
        int d = idx - n * TD;
        const float4* tr = (const float4*)(tokens + n * TD);
        const float4* wr = (const float4*)(Wk + d * TD);
        float acc = 0.0f;
        #pragma unroll
        for (int j = 0; j < TD / 4; ++j) {
            float4 a = tr[j];
            float4 b = wr[j];
            acc = fmaf(a.x, b.x, acc);
            acc = fmaf(a.y, b.y, acc);
            acc = fmaf(a.z, b.z, acc);
            acc = fmaf(a.w, b.w, acc);
        }
        kT[d][n] = fast_tanh(acc);
        tokS[n][d] = tokens[n * TD + d];
    }
    for (int idx = threadIdx.x; idx < TD * NH; idx += TPB) {
        int d = idx >> 2;
        int h = idx & 3;
        wvT[d][h] = Wv[h * TD + d];
    }
    __syncthreads();

    const int gtid = blockIdx.x * TPB + threadIdx.x;
    const int pos = gtid >> 2;      // 4 consecutive lanes share a position
    const int l = gtid & 3;         // lane-in-group
    const int d0 = l * DPL;         // this lane's d-subset start

    // ---- q phase: q[dd] = tanh(x . Wq[d0+dd]) , j-outer so x stays tiny ----
    float q[DPL];
    #pragma unroll
    for (int dd = 0; dd < DPL; ++dd) q[dd] = 0.0f;

    const float4* xr = (const float4*)(ref_emb + (size_t)pos * TD);
    const float* wqBase = Wq + d0 * TD;
    #pragma unroll 2
    for (int j = 0; j < TD / 4; ++j) {
        float4 x4 = xr[j]; // 4 lanes of a group broadcast-read the same 16B
        #pragma unroll
        for (int dd = 0; dd < DPL; ++dd) {
            float4 w = *(const float4*)(wqBase + dd * TD + 4 * j);
            q[dd] = fmaf(x4.x, w.x, q[dd]);
            q[dd] = fmaf(x4.y, w.y, q[dd]);
            q[dd] = fmaf(x4.z, w.z, q[dd]);
            q[dd] = fmaf(x4.w, w.w, q[dd]);
        }
    }
    #pragma unroll
    for (int dd = 0; dd < DPL; ++dd) q[dd] = fast_tanh(q[dd]);

    // ---- s phase: logits[n][h] += tanh(q_d + k[n][d]) * Wv[h][d] ----
    float logits[NT][NH];
    #pragma unroll
    for (int n = 0; n < NT; ++n)
        #pragma unroll
        for (int h = 0; h < NH; ++h) logits[n][h] = 0.0f;

    #pragma unroll 4
    for (int dd = 0; dd < DPL; ++dd) {
        const int d = d0 + dd;
        const float qd = q[dd];
        const float4 wv = *(const float4*)(&wvT[d][0]);
        const float4 ka = *(const float4*)(&kT[d][0]);
        const float4 kb = *(const float4*)(&kT[d][4]);
        const float2 kc = *(const float2*)(&kT[d][8]);
        const float kv[NT] = {ka.x, ka.y, ka.z, ka.w, kb.x, kb.y, kb.z, kb.w, kc.x, kc.y};
        #pragma unroll
        for (int n = 0; n < NT; ++n) {
            float s = fast_tanh(qd + kv[n]);
            logits[n][0] = fmaf(s, wv.x, logits[n][0]);
            logits[n][1] = fmaf(s, wv.y, logits[n][1]);
            logits[n][2] = fmaf(s, wv.z, logits[n][2]);
            logits[n][3] = fmaf(s, wv.w, logits[n][3]);
        }
    }

    // ---- reduce partial logits across the 4-lane group (xor 1, xor 2) ----
    #pragma unroll
    for (int n = 0; n < NT; ++n) {
        #pragma unroll
        for (int h = 0; h < NH; ++h) {
            float v = logits[n][h];
            v += __shfl_xor(v, 1);
            v += __shfl_xor(v, 2);
            logits[n][h] = v;
        }
    }

    // ---- softmax over n per head; wn[n] = mean_h attn[n][h] (redundant x4) --
    float wn[NT];
    #pragma unroll
    for (int n = 0; n < NT; ++n) wn[n] = 0.0f;

    #pragma unroll
    for (int h = 0; h < NH; ++h) {
        float m = logits[0][h];
        #pragma unroll
        for (int n = 1; n < NT; ++n) m = fmaxf(m, logits[n][h]);
        float e[NT];
        float ssum = 0.0f;
        #pragma unroll
        for (int n = 0; n < NT; ++n) {
            e[n] = __expf(logits[n][h] - m);
            ssum += e[n];
        }
        float inv = 0.25f * __builtin_amdgcn_rcpf(ssum);
        #pragma unroll
        for (int n = 0; n < NT; ++n) wn[n] = fmaf(e[n], inv, wn[n]);
    }

    // ---- style: out[pos][d] = sum_n wn[n] * tokens[n][d], this lane's 24 d --
    const float4* t4 = (const float4*)(&tokS[0][0]); // [NT][TD/4] float4 view
    float4* op = (float4*)(out + (size_t)pos * TD + d0);
    #pragma unroll
    for (int j = 0; j < DPL / 4; ++j) {
        float4 o = make_float4(0.f, 0.f, 0.f, 0.f);
        #pragma unroll
        for (int n = 0; n < NT; ++n) {
            float4 t = t4[n * (TD / 4) + l * (DPL / 4) + j];
            o.x = fmaf(wn[n], t.x, o.x);
            o.y = fmaf(wn[n], t.y, o.y);
            o.z = fmaf(wn[n], t.z, o.z);
            o.w = fmaf(wn[n], t.w, o.w);
        }
        op[j] = o;
    }
}

extern "C" void kernel_launch(void* const* d_in, const int* in_sizes, int n_in,
                              void* d_out, int out_size, void* d_ws, size_t ws_size,
                              hipStream_t stream) {
    const float* ref_emb = (const float*)d_in[0];
    const float* tokens  = (const float*)d_in[1];
    const float* Wq      = (const float*)d_in[2];
    const float* Wk      = (const float*)d_in[3];
    const float* Wv      = (const float*)d_in[4];
    float* out = (float*)d_out;

    gst_fused<<<(NPOS * LPP) / TPB, TPB, 0, stream>>>(ref_emb, tokens, Wq, Wk, Wv, out);
}

// Round 3
// 100.031 us; speedup vs baseline: 3.2302x; 3.2302x over previous
//
#include <hip/hip_runtime.h>
#include <cstddef>

#define NT 10            // NUM_TOKENS
#define TD 96            // TOKEN_DIM == REF_DIM
#define NH 4             // NUM_HEADS
#define NPOS (32 * 2048) // B*T positions
#define TPB 256
#define LPP 4            // lanes per position
#define DPL 24           // d's (and x-elements) per lane
#define WQS 100          // Wq LDS row stride in floats (≡4 mod 32, 16B-aligned)

__device__ __forceinline__ float fast_tanh(float x) {
    // tanh(x) = 1 - 2/(exp(2x)+1); exact limits at +/-inf, ~1e-6 rel error
    float e = __expf(2.0f * x);
    return 1.0f - 2.0f * __builtin_amdgcn_rcpf(e + 1.0f);
}

__global__ __launch_bounds__(TPB, 3) void gst_fused(
    const float* __restrict__ ref_emb,
    const float* __restrict__ tokens,
    const float* __restrict__ Wq,
    const float* __restrict__ Wk,
    const float* __restrict__ Wv,
    float* __restrict__ out)
{
    __shared__ __align__(16) float wqS[TD * WQS];   // 38400 B, stride 100
    __shared__ __align__(16) float kT[TD][12];      //  4608 B
    __shared__ __align__(16) float wvT[TD][4];      //  1536 B
    __shared__ __align__(16) float tokS[NT * TD];   //  3840 B   (total 48.4 KB)

    const int pos = (blockIdx.x * TPB + threadIdx.x) >> 2;
    const int l = threadIdx.x & 3;

    // prefetch this lane's x quarter early (independent of LDS staging)
    const float4* xr = (const float4*)(ref_emb + (size_t)pos * TD + l * DPL);
    float4 xq[DPL / 4];
    #pragma unroll
    for (int j = 0; j < DPL / 4; ++j) xq[j] = xr[j];

    // ---- stage Wq into LDS (padded rows) ----
    for (int idx = threadIdx.x; idx < TD * (TD / 4); idx += TPB) {
        int d = idx / (TD / 4);
        int j = idx - d * (TD / 4);
        *(float4*)&wqS[d * WQS + 4 * j] = ((const float4*)Wq)[idx];
    }
    // ---- kT[d][n] = tanh(tokens @ Wk^T); tokS staged ----
    for (int idx = threadIdx.x; idx < NT * TD; idx += TPB) {
        int n = idx / TD;
        int d = idx - n * TD;
        const float4* tr = (const float4*)(tokens + n * TD);
        const float4* wr = (const float4*)(Wk + d * TD);
        float acc = 0.0f;
        #pragma unroll
        for (int j = 0; j < TD / 4; ++j) {
            float4 a = tr[j];
            float4 b = wr[j];
            acc = fmaf(a.x, b.x, acc);
            acc = fmaf(a.y, b.y, acc);
            acc = fmaf(a.z, b.z, acc);
            acc = fmaf(a.w, b.w, acc);
        }
        kT[d][idx % TD == d ? n : n] = 0.0f; // placeholder avoided below
        kT[d][n] = fast_tanh(acc);
        tokS[idx] = tokens[idx]; // tokS[n*TD+d]
    }
    for (int idx = threadIdx.x; idx < TD * NH; idx += TPB) {
        int d = idx >> 2;
        int h = idx & 3;
        wvT[d][h] = Wv[h * TD + d];
    }
    __syncthreads();

    // ---- q phase: lane l computes partial dots on its x-quarter for rows
    //      4*cc..4*cc+3, then 4-lane transpose-reduce -> lane owns d=4*cc+l --
    const int b0 = l & 1, b1 = (l >> 1) & 1;
    float q[DPL];
    #pragma unroll 4
    for (int cc = 0; cc < DPL; ++cc) {
        const float* w0 = &wqS[(4 * cc + 0) * WQS + l * DPL];
        const float* w1 = &wqS[(4 * cc + 1) * WQS + l * DPL];
        const float* w2 = &wqS[(4 * cc + 2) * WQS + l * DPL];
        const float* w3 = &wqS[(4 * cc + 3) * WQS + l * DPL];
        float p0 = 0.f, p1 = 0.f, p2 = 0.f, p3 = 0.f;
        #pragma unroll
        for (int j = 0; j < DPL / 4; ++j) {
            float4 a = xq[j];
            float4 w = *(const float4*)(w0 + 4 * j);
            p0 = fmaf(a.x, w.x, p0); p0 = fmaf(a.y, w.y, p0);
            p0 = fmaf(a.z, w.z, p0); p0 = fmaf(a.w, w.w, p0);
            w = *(const float4*)(w1 + 4 * j);
            p1 = fmaf(a.x, w.x, p1); p1 = fmaf(a.y, w.y, p1);
            p1 = fmaf(a.z, w.z, p1); p1 = fmaf(a.w, w.w, p1);
            w = *(const float4*)(w2 + 4 * j);
            p2 = fmaf(a.x, w.x, p2); p2 = fmaf(a.y, w.y, p2);
            p2 = fmaf(a.z, w.z, p2); p2 = fmaf(a.w, w.w, p2);
            w = *(const float4*)(w3 + 4 * j);
            p3 = fmaf(a.x, w.x, p3); p3 = fmaf(a.y, w.y, p3);
            p3 = fmaf(a.z, w.z, p3); p3 = fmaf(a.w, w.w, p3);
        }
        // transpose-reduce across the 4-lane group
        float pa0 = b0 ? p1 : p0;  // p[b0]
        float pa1 = b0 ? p0 : p1;  // p[b0^1]
        float pb0 = b0 ? p3 : p2;  // p[2+b0]
        float pb1 = b0 ? p2 : p3;  // p[2+b0^1]
        float y0 = pa0 + __shfl_xor(pa1, 1);
        float y1 = pb0 + __shfl_xor(pb1, 1);
        float z0 = b1 ? y1 : y0;   // y[b1]
        float z1 = b1 ? y0 : y1;   // y[b1^1]
        q[cc] = fast_tanh(z0 + __shfl_xor(z1, 2));
    }

    // ---- s phase: logits[n][h] += tanh(q_d + kT[d][n]) * wvT[d][h],
    //      lane handles d = 4*cc + l (strided -> conflict-free LDS banks) ----
    float logits[NT][NH];
    #pragma unroll
    for (int n = 0; n < NT; ++n)
        #pragma unroll
        for (int h = 0; h < NH; ++h) logits[n][h] = 0.0f;

    #pragma unroll 4
    for (int cc = 0; cc < DPL; ++cc) {
        const int d = 4 * cc + l;
        const float qd = q[cc];
        const float4 wv = *(const float4*)(&wvT[d][0]);
        const float4 ka = *(const float4*)(&kT[d][0]);
        const float4 kb = *(const float4*)(&kT[d][4]);
        const float2 kc = *(const float2*)(&kT[d][8]);
        const float kv[NT] = {ka.x, ka.y, ka.z, ka.w, kb.x, kb.y, kb.z, kb.w, kc.x, kc.y};
        #pragma unroll
        for (int n = 0; n < NT; ++n) {
            float s = fast_tanh(qd + kv[n]);
            logits[n][0] = fmaf(s, wv.x, logits[n][0]);
            logits[n][1] = fmaf(s, wv.y, logits[n][1]);
            logits[n][2] = fmaf(s, wv.z, logits[n][2]);
            logits[n][3] = fmaf(s, wv.w, logits[n][3]);
        }
    }

    // ---- reduce logits across the 4-lane group ----
    #pragma unroll
    for (int n = 0; n < NT; ++n) {
        #pragma unroll
        for (int h = 0; h < NH; ++h) {
            float v = logits[n][h];
            v += __shfl_xor(v, 1);
            v += __shfl_xor(v, 2);
            logits[n][h] = v;
        }
    }

    // ---- softmax over n per head; wn[n] = mean_h attn (replicated x4) ----
    float wn[NT];
    #pragma unroll
    for (int n = 0; n < NT; ++n) wn[n] = 0.0f;
    #pragma unroll
    for (int h = 0; h < NH; ++h) {
        float m = logits[0][h];
        #pragma unroll
        for (int n = 1; n < NT; ++n) m = fmaxf(m, logits[n][h]);
        float e[NT];
        float ssum = 0.0f;
        #pragma unroll
        for (int n = 0; n < NT; ++n) {
            e[n] = __expf(logits[n][h] - m);
            ssum += e[n];
        }
        float inv = 0.25f * __builtin_amdgcn_rcpf(ssum);
        #pragma unroll
        for (int n = 0; n < NT; ++n) wn[n] = fmaf(e[n], inv, wn[n]);
    }

    // ---- style: blocked d for contiguous float4 stores (wn replicated) ----
    const float4* t4 = (const float4*)tokS;
    float4* op = (float4*)(out + (size_t)pos * TD + l * DPL);
    #pragma unroll
    for (int j = 0; j < DPL / 4; ++j) {
        float4 o = make_float4(0.f, 0.f, 0.f, 0.f);
        #pragma unroll
        for (int n = 0; n < NT; ++n) {
            float4 t = t4[n * (TD / 4) + l * (DPL / 4) + j];
            o.x = fmaf(wn[n], t.x, o.x);
            o.y = fmaf(wn[n], t.y, o.y);
            o.z = fmaf(wn[n], t.z, o.z);
            o.w = fmaf(wn[n], t.w, o.w);
        }
        op[j] = o;
    }
}

extern "C" void kernel_launch(void* const* d_in, const int* in_sizes, int n_in,
                              void* d_out, int out_size, void* d_ws, size_t ws_size,
                              hipStream_t stream) {
    const float* ref_emb = (const float*)d_in[0];
    const float* tokens  = (const float*)d_in[1];
    const float* Wq      = (const float*)d_in[2];
    const float* Wk      = (const float*)d_in[3];
    const float* Wv      = (const float*)d_in[4];
    float* out = (float*)d_out;

    gst_fused<<<(NPOS * LPP) / TPB, TPB, 0, stream>>>(ref_emb, tokens, Wq, Wk, Wv, out);
}

// Round 5
// 97.223 us; speedup vs baseline: 3.3234x; 1.0289x over previous
//
#include <hip/hip_runtime.h>
#include <cstddef>

#define NT 10            // NUM_TOKENS
#define TD 96            // TOKEN_DIM == REF_DIM
#define NH 4             // NUM_HEADS
#define NPOS (32 * 2048) // B*T positions
#define TPB 256
#define LPP 4            // lanes per position
#define DPL 24           // d's (and x-elements) per lane

typedef _Float16 h2 __attribute__((ext_vector_type(2)));

__device__ __forceinline__ h2 pack_h2(float a, float b) {
    // cvt_pkrtz returns __fp16 ext_vector(2); bit-identical to h2
    return __builtin_bit_cast(h2, __builtin_amdgcn_cvt_pkrtz(a, b));
}

__device__ __forceinline__ float fast_tanh(float x) {
    // tanh(x) = 1 - 2/(exp(2x)+1); exact limits at +/-inf, ~1e-6 rel error
    float e = __expf(2.0f * x);
    return 1.0f - 2.0f * __builtin_amdgcn_rcpf(e + 1.0f);
}

__device__ __forceinline__ float dot2acc(h2 a, h2 b, float c) {
#if __has_builtin(__builtin_amdgcn_fdot2)
    return __builtin_amdgcn_fdot2(a, b, c, false);
#else
    c = fmaf((float)a[0], (float)b[0], c);
    return fmaf((float)a[1], (float)b[1], c);
#endif
}

__global__ __launch_bounds__(TPB, 6) void gst_fused(
    const float* __restrict__ ref_emb,
    const float* __restrict__ tokens,
    const float* __restrict__ Wq,
    const float* __restrict__ Wk,
    const float* __restrict__ Wv,
    float* __restrict__ out)
{
    // Wq staged as f16 pairs, row-major [96][48] h2 = 18432 B (no pad needed:
    // lane quarter offsets l*12 h2 = l*12 dwords -> banks {0,12,24,4}, distinct)
    __shared__ __align__(16) h2 wqH[TD][TD / 2];
    // kT2[d][n] = tanh(tanh(tokens @ Wk^T)) (pre-tanh'd for addition formula)
    __shared__ __align__(16) float kT2[TD][12]; // 4608 B
    __shared__ __align__(16) float wvT[TD][4];  // 1536 B   (total 24576 B)

    const int pos = (blockIdx.x * TPB + threadIdx.x) >> 2;
    const int l = threadIdx.x & 3;

    // prefetch this lane's x quarter (fp32) early
    const float4* xr = (const float4*)(ref_emb + (size_t)pos * TD + l * DPL);
    float4 xf[DPL / 4];
    #pragma unroll
    for (int j = 0; j < DPL / 4; ++j) xf[j] = xr[j];

    // ---- stage Wq -> LDS as f16 ----
    for (int idx = threadIdx.x; idx < TD * TD / 2; idx += TPB) {
        float2 f = ((const float2*)Wq)[idx];
        ((h2*)wqH)[idx] = pack_h2(f.x, f.y);
    }
    // ---- kT2[d][n] = tanh(tanh(tokens . Wk[d])) ----
    for (int idx = threadIdx.x; idx < NT * TD; idx += TPB) {
        int n = idx / TD;
        int d = idx - n * TD;
        const float4* tr = (const float4*)(tokens + n * TD);
        const float4* wr = (const float4*)(Wk + d * TD);
        float acc = 0.0f;
        #pragma unroll
        for (int j = 0; j < TD / 4; ++j) {
            float4 a = tr[j];
            float4 b = wr[j];
            acc = fmaf(a.x, b.x, acc);
            acc = fmaf(a.y, b.y, acc);
            acc = fmaf(a.z, b.z, acc);
            acc = fmaf(a.w, b.w, acc);
        }
        kT2[d][n] = fast_tanh(fast_tanh(acc));
    }
    for (int idx = threadIdx.x; idx < TD * NH; idx += TPB) {
        int d = idx >> 2;
        int h = idx & 3;
        wvT[d][h] = Wv[h * TD + d];
    }

    // convert x quarter to f16 pairs while staging completes
    h2 xh[DPL / 2];
    #pragma unroll
    for (int j = 0; j < DPL / 4; ++j) {
        xh[2 * j + 0] = pack_h2(xf[j].x, xf[j].y);
        xh[2 * j + 1] = pack_h2(xf[j].z, xf[j].w);
    }
    __syncthreads();

    const int b0 = l & 1, b1 = (l >> 1) & 1;

    float logits[NT][NH];
    #pragma unroll
    for (int n = 0; n < NT; ++n)
        #pragma unroll
        for (int h = 0; h < NH; ++h) logits[n][h] = 0.0f;

    // ---- fused q + s phase, one d-group (4 rows) per iteration ----
    #pragma unroll 2
    for (int cc = 0; cc < DPL; ++cc) {
        // partial dots: lane's x-quarter vs rows 4cc..4cc+3 of Wq
        const h2* w0 = &wqH[4 * cc + 0][l * (DPL / 2)];
        const h2* w1 = &wqH[4 * cc + 1][l * (DPL / 2)];
        const h2* w2 = &wqH[4 * cc + 2][l * (DPL / 2)];
        const h2* w3 = &wqH[4 * cc + 3][l * (DPL / 2)];
        float p0 = 0.f, p1 = 0.f, p2 = 0.f, p3 = 0.f;
        #pragma unroll
        for (int j = 0; j < DPL / 2; ++j) {
            p0 = dot2acc(xh[j], w0[j], p0);
            p1 = dot2acc(xh[j], w1[j], p1);
            p2 = dot2acc(xh[j], w2[j], p2);
            p3 = dot2acc(xh[j], w3[j], p3);
        }
        // 4-lane transpose-reduce -> lane owns d = 4*cc + l
        float pa0 = b0 ? p1 : p0;
        float pa1 = b0 ? p0 : p1;
        float pb0 = b0 ? p3 : p2;
        float pb1 = b0 ? p2 : p3;
        float y0 = pa0 + __shfl_xor(pa1, 1);
        float y1 = pb0 + __shfl_xor(pb1, 1);
        float z0 = b1 ? y1 : y0;
        float z1 = b1 ? y0 : y1;
        // tq = tanh(q) where q = tanh(raw)  (for the addition formula)
        float tq = fast_tanh(fast_tanh(z0 + __shfl_xor(z1, 2)));

        // s phase for d = 4cc + l: s = (tq + tk)/(1 + tq*tk)  [exact tanh(q+k)]
        const int d = 4 * cc + l;
        const float4 wv = *(const float4*)(&wvT[d][0]);
        const float4 ka = *(const float4*)(&kT2[d][0]);
        const float4 kb = *(const float4*)(&kT2[d][4]);
        const float2 kc = *(const float2*)(&kT2[d][8]);
        const float kv[NT] = {ka.x, ka.y, ka.z, ka.w, kb.x, kb.y, kb.z, kb.w, kc.x, kc.y};
        #pragma unroll
        for (int n = 0; n < NT; ++n) {
            float num = tq + kv[n];
            float den = fmaf(tq, kv[n], 1.0f);
            float s = num * __builtin_amdgcn_rcpf(den);
            logits[n][0] = fmaf(s, wv.x, logits[n][0]);
            logits[n][1] = fmaf(s, wv.y, logits[n][1]);
            logits[n][2] = fmaf(s, wv.z, logits[n][2]);
            logits[n][3] = fmaf(s, wv.w, logits[n][3]);
        }
    }

    // ---- reduce logits across the 4-lane group ----
    #pragma unroll
    for (int n = 0; n < NT; ++n) {
        #pragma unroll
        for (int h = 0; h < NH; ++h) {
            float v = logits[n][h];
            v += __shfl_xor(v, 1);
            v += __shfl_xor(v, 2);
            logits[n][h] = v;
        }
    }

    // ---- softmax over n per head; wn[n] = mean_h attn (replicated x4) ----
    float wn[NT];
    #pragma unroll
    for (int n = 0; n < NT; ++n) wn[n] = 0.0f;
    #pragma unroll
    for (int h = 0; h < NH; ++h) {
        float m = logits[0][h];
        #pragma unroll
        for (int n = 1; n < NT; ++n) m = fmaxf(m, logits[n][h]);
        float e[NT];
        float ssum = 0.0f;
        #pragma unroll
        for (int n = 0; n < NT; ++n) {
            e[n] = __expf(logits[n][h] - m);
            ssum += e[n];
        }
        float inv = 0.25f * __builtin_amdgcn_rcpf(ssum);
        #pragma unroll
        for (int n = 0; n < NT; ++n) wn[n] = fmaf(e[n], inv, wn[n]);
    }

    // ---- style: out[pos][d] = sum_n wn[n]*tokens[n][d]; L1-resident tokens --
    float4* op = (float4*)(out + (size_t)pos * TD + l * DPL);
    const float4* t4 = (const float4*)tokens;
    #pragma unroll
    for (int j = 0; j < DPL / 4; ++j) {
        float4 o = make_float4(0.f, 0.f, 0.f, 0.f);
        #pragma unroll
        for (int n = 0; n < NT; ++n) {
            float4 t = t4[n * (TD / 4) + l * (DPL / 4) + j];
            o.x = fmaf(wn[n], t.x, o.x);
            o.y = fmaf(wn[n], t.y, o.y);
            o.z = fmaf(wn[n], t.z, o.z);
            o.w = fmaf(wn[n], t.w, o.w);
        }
        op[j] = o;
    }
}

extern "C" void kernel_launch(void* const* d_in, const int* in_sizes, int n_in,
                              void* d_out, int out_size, void* d_ws, size_t ws_size,
                              hipStream_t stream) {
    const float* ref_emb = (const float*)d_in[0];
    const float* tokens  = (const float*)d_in[1];
    const float* Wq      = (const float*)d_in[2];
    const float* Wk      = (const float*)d_in[3];
    const float* Wv      = (const float*)d_in[4];
    float* out = (float*)d_out;

    gst_fused<<<(NPOS * LPP) / TPB, TPB, 0, stream>>>(ref_emb, tokens, Wq, Wk, Wv, out);
}

// Round 6
// 61.427 us; speedup vs baseline: 5.2602x; 1.5828x over previous
//
#include <hip/hip_runtime.h>
#include <cstddef>

#define NT 10            // NUM_TOKENS
#define TD 96            // TOKEN_DIM == REF_DIM
#define NH 4             // NUM_HEADS
#define NPOS (32 * 2048) // B*T positions
#define TPB 256
#define LPP 8            // lanes per position
#define XPL 12           // x elems per lane (TD / LPP)

// workspace layout (bytes) — also the LDS layout of the main kernel
#define WS_WQ 0          // h2    wqH[96][48]  (18432 B)
#define WS_KT 18432      // float kT2[96][12]  ( 4608 B) rows padded 10->12
#define WS_WV 23040      // float wvT[96][4]   ( 1536 B)
#define WS_BYTES 24576

typedef _Float16 h2 __attribute__((ext_vector_type(2)));

__device__ __forceinline__ h2 pack_h2(float a, float b) {
    return __builtin_bit_cast(h2, __builtin_amdgcn_cvt_pkrtz(a, b));
}

__device__ __forceinline__ float fast_tanh(float x) {
    // tanh(x) = 1 - 2/(exp(2x)+1); exact limits at +/-inf, ~1e-6 rel error
    float e = __expf(2.0f * x);
    return 1.0f - 2.0f * __builtin_amdgcn_rcpf(e + 1.0f);
}

__device__ __forceinline__ float dot2acc(h2 a, h2 b, float c) {
#if __has_builtin(__builtin_amdgcn_fdot2)
    return __builtin_amdgcn_fdot2(a, b, c, false);
#else
    c = fmaf((float)a[0], (float)b[0], c);
    return fmaf((float)a[1], (float)b[1], c);
#endif
}

// ---- prep kernel: 8 blocks, block b owns d-slice [12b, 12b+12) ----
__global__ __launch_bounds__(TPB) void gst_prep(
    const float* __restrict__ tokens,
    const float* __restrict__ Wq,
    const float* __restrict__ Wk,
    const float* __restrict__ Wv,
    char* __restrict__ ws)
{
    h2* wqH = (h2*)(ws + WS_WQ);
    float* kT2 = (float*)(ws + WS_KT);
    float* wvT = (float*)(ws + WS_WV);
    const int b = blockIdx.x;

    // Wq rows -> f16 pairs
    for (int idx = threadIdx.x; idx < 12 * (TD / 2); idx += TPB) {
        int r = 12 * b + idx / (TD / 2);
        int c = idx % (TD / 2);
        float2 f = ((const float2*)(Wq + r * TD))[c];
        wqH[r * (TD / 2) + c] = pack_h2(f.x, f.y);
    }
    // kT2[d][n] = tanh(tanh(tokens[n] . Wk[d]))  (pre-tanh'd, addition formula)
    for (int idx = threadIdx.x; idx < 12 * NT; idx += TPB) {
        int d = 12 * b + idx / NT;
        int n = idx % NT;
        const float4* tr = (const float4*)(tokens + n * TD);
        const float4* wr = (const float4*)(Wk + d * TD);
        float acc = 0.0f;
        #pragma unroll
        for (int j = 0; j < TD / 4; ++j) {
            float4 a = tr[j];
            float4 w = wr[j];
            acc = fmaf(a.x, w.x, acc);
            acc = fmaf(a.y, w.y, acc);
            acc = fmaf(a.z, w.z, acc);
            acc = fmaf(a.w, w.w, acc);
        }
        kT2[d * 12 + n] = fast_tanh(fast_tanh(acc));
    }
    // wvT[d][h] = Wv[h][d]
    for (int idx = threadIdx.x; idx < 12 * NH; idx += TPB) {
        int d = 12 * b + (idx >> 2);
        int h = idx & 3;
        wvT[d * 4 + h] = Wv[h * TD + d];
    }
}

// ---- main kernel: 8 lanes per position ----
__global__ __launch_bounds__(TPB, 6) void gst_main(
    const float* __restrict__ ref_emb,
    const float* __restrict__ tokens,
    const char* __restrict__ ws,
    float* __restrict__ out)
{
    __shared__ __align__(16) char lds[WS_BYTES];
    const h2* wqS = (const h2*)(lds + WS_WQ);
    const float* kTS = (const float*)(lds + WS_KT);
    const float* wvS = (const float*)(lds + WS_WV);

    const int tid = threadIdx.x;
    const int pos = (blockIdx.x * TPB + tid) >> 3;
    const int l = tid & 7;

    // prefetch this lane's x twelfth (3 float4), overlapping the LDS copy
    const float4* xr = (const float4*)(ref_emb + (size_t)pos * TD + l * XPL);
    float4 x0 = xr[0], x1 = xr[1], x2 = xr[2];

    // stage ws -> LDS: pure linear copy, 6 float4 per thread
    {
        const float4* src = (const float4*)ws;
        float4* dst = (float4*)lds;
        #pragma unroll
        for (int i = 0; i < WS_BYTES / 16 / TPB; ++i)
            dst[tid + i * TPB] = src[tid + i * TPB];
    }

    h2 xh[6];
    xh[0] = pack_h2(x0.x, x0.y); xh[1] = pack_h2(x0.z, x0.w);
    xh[2] = pack_h2(x1.x, x1.y); xh[3] = pack_h2(x1.z, x1.w);
    xh[4] = pack_h2(x2.x, x2.y); xh[5] = pack_h2(x2.z, x2.w);
    __syncthreads();

    float logits[NT][NH];
    #pragma unroll
    for (int n = 0; n < NT; ++n)
        #pragma unroll
        for (int h = 0; h < NH; ++h) logits[n][h] = 0.0f;

    // ---- fused q + s phase: 12 groups of 8 d's ----
    #pragma unroll 2
    for (int cc = 0; cc < 12; ++cc) {
        // partial dots, row-relative indexing: p[i] = partial of row (l^i)
        float p[8];
        #pragma unroll
        for (int i = 0; i < 8; ++i) {
            const h2* w = &wqS[(8 * cc + (l ^ i)) * (TD / 2) + l * (XPL / 2)];
            float a = 0.0f;
            #pragma unroll
            for (int j = 0; j < XPL / 2; ++j) a = dot2acc(xh[j], w[j], a);
            p[i] = a;
        }
        // select-free xor butterfly: p[i] holds row l^i -> partner has it at i^m
        p[0] += __shfl_xor(p[1], 1);
        p[2] += __shfl_xor(p[3], 1);
        p[4] += __shfl_xor(p[5], 1);
        p[6] += __shfl_xor(p[7], 1);
        p[0] += __shfl_xor(p[2], 2);
        p[4] += __shfl_xor(p[6], 2);
        p[0] += __shfl_xor(p[4], 4);

        // tq = tanh(q), q = tanh(raw)   (for the exact tanh addition formula)
        const float tq = fast_tanh(fast_tanh(p[0]));

        // s phase for d = 8*cc + l: s = (tq + tk)/(1 + tq*tk) = tanh(q + k)
        const int d = 8 * cc + l;
        const float4 wv = *(const float4*)&wvS[d * 4];
        const float4 ka = *(const float4*)&kTS[d * 12];
        const float4 kb = *(const float4*)&kTS[d * 12 + 4];
        const float2 kc = *(const float2*)&kTS[d * 12 + 8];
        const float kv[NT] = {ka.x, ka.y, ka.z, ka.w, kb.x, kb.y, kb.z, kb.w, kc.x, kc.y};
        #pragma unroll
        for (int n = 0; n < NT; ++n) {
            float num = tq + kv[n];
            float den = fmaf(tq, kv[n], 1.0f);
            float s = num * __builtin_amdgcn_rcpf(den);
            logits[n][0] = fmaf(s, wv.x, logits[n][0]);
            logits[n][1] = fmaf(s, wv.y, logits[n][1]);
            logits[n][2] = fmaf(s, wv.z, logits[n][2]);
            logits[n][3] = fmaf(s, wv.w, logits[n][3]);
        }
    }

    // ---- reduce logits across the 8-lane group ----
    #pragma unroll
    for (int n = 0; n < NT; ++n) {
        #pragma unroll
        for (int h = 0; h < NH; ++h) {
            float v = logits[n][h];
            v += __shfl_xor(v, 1);
            v += __shfl_xor(v, 2);
            v += __shfl_xor(v, 4);
            logits[n][h] = v;
        }
    }

    // ---- softmax over n per head; wn[n] = mean_h attn (replicated x8) ----
    float wn[NT];
    #pragma unroll
    for (int n = 0; n < NT; ++n) wn[n] = 0.0f;
    #pragma unroll
    for (int h = 0; h < NH; ++h) {
        float m = logits[0][h];
        #pragma unroll
        for (int n = 1; n < NT; ++n) m = fmaxf(m, logits[n][h]);
        float e[NT];
        float ssum = 0.0f;
        #pragma unroll
        for (int n = 0; n < NT; ++n) {
            e[n] = __expf(logits[n][h] - m);
            ssum += e[n];
        }
        float inv = 0.25f * __builtin_amdgcn_rcpf(ssum);
        #pragma unroll
        for (int n = 0; n < NT; ++n) wn[n] = fmaf(e[n], inv, wn[n]);
    }

    // ---- style + store, coalesced: lane handles float4-index l + 8*jj ----
    float4* ob = (float4*)(out + (size_t)pos * TD);
    const float4* t4 = (const float4*)tokens;
    #pragma unroll
    for (int jj = 0; jj < 3; ++jj) {
        const int d4 = l + 8 * jj;
        float4 o = make_float4(0.f, 0.f, 0.f, 0.f);
        #pragma unroll
        for (int n = 0; n < NT; ++n) {
            float4 t = t4[n * (TD / 4) + d4];
            o.x = fmaf(wn[n], t.x, o.x);
            o.y = fmaf(wn[n], t.y, o.y);
            o.z = fmaf(wn[n], t.z, o.z);
            o.w = fmaf(wn[n], t.w, o.w);
        }
        ob[d4] = o;
    }
}

extern "C" void kernel_launch(void* const* d_in, const int* in_sizes, int n_in,
                              void* d_out, int out_size, void* d_ws, size_t ws_size,
                              hipStream_t stream) {
    const float* ref_emb = (const float*)d_in[0];
    const float* tokens  = (const float*)d_in[1];
    const float* Wq      = (const float*)d_in[2];
    const float* Wk      = (const float*)d_in[3];
    const float* Wv      = (const float*)d_in[4];
    float* out = (float*)d_out;

    gst_prep<<<8, TPB, 0, stream>>>(tokens, Wq, Wk, Wv, (char*)d_ws);
    gst_main<<<(NPOS * LPP) / TPB, TPB, 0, stream>>>(ref_emb, tokens,
                                                     (const char*)d_ws, out);
}